// Round 2
// baseline (169.580 us; speedup 1.0000x reference)
//
#include <hip/hip_runtime.h>
#include <hip/hip_bf16.h>
#include <float.h>

#define B_    16
#define N1_   4096
#define N2_   1024
#define C2_   256
#define OUT_  256
#define K_    4096    // GEMM K == N1
#define SPLITK 8
#define KCH_  (K_ / SPLITK)     // 512
#define ZSLAB 1048576           // floats per partial slab (16*256*256)

typedef short short8 __attribute__((ext_vector_type(8)));
typedef float float4v __attribute__((ext_vector_type(4)));

static __device__ __forceinline__ unsigned short f32_to_bf16_bits(float v) {
    __hip_bfloat16 h = __float2bfloat16(v);
    return *(unsigned short*)&h;
}

// ---------------------------------------------------------------------------
// Fused (w1cvt + knn + interp), block-role branch.
// R15: occupancy attack. R14 post-mortem showed the knn kernel is not
// distance-loop-bound; it is phase-serialized at 4 blocks/CU (LDS 34.8 KB),
// so the gather phase runs latency-bound at 2.65 TB/s. Shrink LDS to 21.2 KB
// -> 7 blocks/CU so different blocks' compute/gather phases overlap:
//  - pf[64][49] (12.5 KB) replaced by in-wave __shfl_xor merge (xor 16,32)
//    across the 4 slice-lanes sharing the same queries; each wave writes
//    only merged top-3 -> pf[4][64][3] (3 KB). Final merge: 12 inserts.
//  - transpose tile halved: two 32-query passes, tile[256][33] (16.9 KB).
// Distance key packing identical to R9/R11 (index in low 10 mantissa bits,
// smaller index wins ties); winners recomputed exactly. absmax unchanged.
// ---------------------------------------------------------------------------
#define TPAD2 33
struct KnnSh {
    float4 pts[16][65];       // per-slice padded candidates   16.64 KB
    float  pf[4][64][3];      // per-wave merged top-3          3.00 KB
};
union ShUnion {
    KnnSh a;
    unsigned short tile[C2_][TPAD2];  // half-transpose tile   16.90 KB
};

__global__ __launch_bounds__(256) void knn_interp_kernel(
    const float* __restrict__ xyz1,
    const float* __restrict__ xyz2,
    const float* __restrict__ x2,
    unsigned short* __restrict__ interp_t,
    const float* __restrict__ W1,
    unsigned short* __restrict__ W1b,
    float* __restrict__ accum)
{
    __shared__ ShUnion sh;
    __shared__ float rw[64][3];
    __shared__ int   ri[64][3];

    const int bid = blockIdx.x;
    const int t   = threadIdx.x;

    if (bid < 1024) {   // ---- role: W1 convert (+ accum zero) ----
        if (bid == 0) {
            accum[t] = 0.0f;
            accum[256 + t] = 0.0f;
        }
        const int i = (bid * 256 + t) * 4;
        float4 v = *(const float4*)(W1 + i);
        ushort4 o;
        o.x = f32_to_bf16_bits(v.x);
        o.y = f32_to_bf16_bits(v.y);
        o.z = f32_to_bf16_bits(v.z);
        o.w = f32_to_bf16_bits(v.w);
        *(ushort4*)(W1b + i) = o;
        return;
    }

    // ---- role: knn + interp ----
    const int rem = bid - 1024;
    const int b   = rem >> 6;
    const int n0  = (rem & 63) * 64;
    const int w   = t >> 6;
    const int l   = t & 63;

    for (int r = 0; r < 4; ++r) {
        int j = r * 256 + t;
        const float* p = xyz2 + ((size_t)b * N2_ + j) * 3;
        float x = p[0], y = p[1], z = p[2];
        sh.a.pts[j >> 6][j & 63] = make_float4(x, y, z, 0.5f * ((x * x + y * y) + z * z));
    }
    __syncthreads();

    const int qg    = l & 15;           // query group: 4 queries per lane
    const int slice = (w << 2) | (l >> 4);   // 16 slices of 64 candidates
    const int jbase = slice << 6;

    // load this lane's 4 queries (12 consecutive floats, 48B aligned)
    const float* qb = xyz1 + ((size_t)b * N1_ + n0 + qg * 4) * 3;
    float4 v0 = ((const float4*)qb)[0];
    float4 v1 = ((const float4*)qb)[1];
    float4 v2 = ((const float4*)qb)[2];
    float qx[4] = {v0.x, v0.w, v1.z, v2.y};
    float qy[4] = {v0.y, v1.x, v1.w, v2.z};
    float qz[4] = {v0.z, v1.y, v2.x, v2.w};

    float ns0[4], ns1[4], ns2[4], ss[4], f[4][3];
    #pragma unroll
    for (int i = 0; i < 4; ++i) {
        ns0[i] = -qx[i]; ns1[i] = -qy[i]; ns2[i] = -qz[i];
        ss[i]  = (qx[i] * qx[i] + qy[i] * qy[i]) + qz[i] * qz[i];
        f[i][0] = FLT_MAX; f[i][1] = FLT_MAX; f[i][2] = FLT_MAX;
    }

    #pragma unroll 2
    for (int jj = 0; jj < 64; ++jj) {
        float4 pq = sh.a.pts[slice][jj];
        int j = jbase + jj;
        #pragma unroll
        for (int i = 0; i < 4; ++i) {
            float acc = fmaf(ns0[i], pq.x, pq.w);
            acc = fmaf(ns1[i], pq.y, acc);
            acc = fmaf(ns2[i], pq.z, acc);
            float dk = fmaxf(fmaf(2.0f, acc, ss[i]), 0.0f);
            float fp = __int_as_float((__float_as_int(dk) & 0xFFFFFC00) | j);
            float nf0 = fminf(fp, f[i][0]);
            float nf1 = __builtin_amdgcn_fmed3f(fp, f[i][0], f[i][1]);
            float nf2 = fminf(f[i][2], fmaxf(fp, f[i][1]));
            f[i][0] = nf0; f[i][1] = nf1; f[i][2] = nf2;
        }
    }

    // in-wave merge across the 4 slice-lanes sharing the same queries
    #pragma unroll
    for (int x = 16; x <= 32; x <<= 1) {
        #pragma unroll
        for (int i = 0; i < 4; ++i) {
            float h0 = __shfl_xor(f[i][0], x);
            float h1 = __shfl_xor(f[i][1], x);
            float h2 = __shfl_xor(f[i][2], x);
            float t0, t1, t2;
            t0 = fminf(h0, f[i][0]);
            t1 = __builtin_amdgcn_fmed3f(h0, f[i][0], f[i][1]);
            t2 = fminf(f[i][2], fmaxf(h0, f[i][1]));
            f[i][0] = t0; f[i][1] = t1; f[i][2] = t2;
            t0 = fminf(h1, f[i][0]);
            t1 = __builtin_amdgcn_fmed3f(h1, f[i][0], f[i][1]);
            t2 = fminf(f[i][2], fmaxf(h1, f[i][1]));
            f[i][0] = t0; f[i][1] = t1; f[i][2] = t2;
            t0 = fminf(h2, f[i][0]);
            t1 = __builtin_amdgcn_fmed3f(h2, f[i][0], f[i][1]);
            t2 = fminf(f[i][2], fmaxf(h2, f[i][1]));
            f[i][0] = t0; f[i][1] = t1; f[i][2] = t2;
        }
    }
    if ((l >> 4) == 0) {
        #pragma unroll
        for (int i = 0; i < 4; ++i)
        #pragma unroll
        for (int r = 0; r < 3; ++r)
            sh.a.pf[w][l * 4 + i][r] = f[i][r];
    }
    __syncthreads();

    if (w == 0) {
        float g0 = FLT_MAX, g1 = FLT_MAX, g2 = FLT_MAX;
        #pragma unroll
        for (int p = 0; p < 4; ++p)
        #pragma unroll
        for (int r = 0; r < 3; ++r) {
            float fp = sh.a.pf[p][l][r];
            float n0v = fminf(fp, g0);
            float n1v = __builtin_amdgcn_fmed3f(fp, g0, g1);
            float n2v = fminf(g2, fmaxf(fp, g1));
            g0 = n0v; g1 = n1v; g2 = n2v;
        }
        int j0 = __float_as_int(g0) & 1023;
        int j1 = __float_as_int(g1) & 1023;
        int j2 = __float_as_int(g2) & 1023;
        const float4 p0 = sh.a.pts[j0 >> 6][j0 & 63];
        const float4 p1 = sh.a.pts[j1 >> 6][j1 & 63];
        const float4 p2 = sh.a.pts[j2 >> 6][j2 & 63];
        // recompute exact distances for THIS query (lane l = local query id)
        const float* q = xyz1 + ((size_t)b * N1_ + n0 + l) * 3;
        const float s0 = q[0], s1 = q[1], s2 = q[2];
        const float ssl = (s0 * s0 + s1 * s1) + s2 * s2;
        float dd0 = ssl + 2.0f * (p0.w - ((s0 * p0.x + s1 * p0.y) + s2 * p0.z));
        float dd1 = ssl + 2.0f * (p1.w - ((s0 * p1.x + s1 * p1.y) + s2 * p1.z));
        float dd2 = ssl + 2.0f * (p2.w - ((s0 * p2.x + s1 * p2.y) + s2 * p2.z));
        float r0 = 1.0f / (dd0 + 1e-8f);
        float r1 = 1.0f / (dd1 + 1e-8f);
        float r2 = 1.0f / (dd2 + 1e-8f);
        float sden = (r0 + r1) + r2;
        rw[l][0] = r0 / sden;  rw[l][1] = r1 / sden;  rw[l][2] = r2 / sden;
        ri[l][0] = j0;         ri[l][1] = j1;         ri[l][2] = j2;
    }
    __syncthreads();   // rw/ri ready; pts/pf dead -> tile may alias

    // phase B in two 32-query half-passes (tile[256][33])
    for (int half = 0; half < 2; ++half) {
        for (int p = 0; p < 8; ++p) {
            int nlc = p * 4 + w;             // tile column 0..31
            int nl  = half * 32 + nlc;       // query 0..63
            float w0 = rw[nl][0], w1 = rw[nl][1], w2 = rw[nl][2];
            int i0g = ri[nl][0], i1g = ri[nl][1], i2g = ri[nl][2];
            const float4 va = ((const float4*)(x2 + ((size_t)b * N2_ + i0g) * C2_))[l];
            const float4 vb = ((const float4*)(x2 + ((size_t)b * N2_ + i1g) * C2_))[l];
            const float4 vc = ((const float4*)(x2 + ((size_t)b * N2_ + i2g) * C2_))[l];
            float fa[4] = {va.x, va.y, va.z, va.w};
            float fb[4] = {vb.x, vb.y, vb.z, vb.w};
            float fc[4] = {vc.x, vc.y, vc.z, vc.w};
            #pragma unroll
            for (int i = 0; i < 4; ++i) {
                float v = w0 * fa[i];
                v = fmaf(w1, fb[i], v);
                v = fmaf(w2, fc[i], v);
                sh.tile[l * 4 + i][nlc] = f32_to_bf16_bits(v);
            }
        }
        __syncthreads();

        for (int r = 0; r < 32; ++r) {
            int c   = r * 8 + w * 2 + (l >> 5);
            int col = l & 31;
            interp_t[((size_t)b * C2_ + c) * K_ + n0 + half * 32 + col] = sh.tile[c][col];
        }
        __syncthreads();
    }
}

// ---------------------------------------------------------------------------
// Kernel 3: split-K GEMM, tile 128(o) x 64(c), BK=64 -> 8 iterations
// (R13 showed the stall is barrier count, not load latency: halve barriers,
// same LDS instr count per K-element). Register prefetch retained.
// Grid 4(c) x 2(o) x 128 = 1024 blocks -> 4 blocks/CU (LDS 27.6 KB).
// ---------------------------------------------------------------------------
#define LDA 72
__global__ __launch_bounds__(256) void gemm_kernel(
    const unsigned short* __restrict__ W1b,
    const unsigned short* __restrict__ interp_t,
    float* __restrict__ Zp)
{
    __shared__ unsigned short Alds[128][LDA];   // 18.4 KB
    __shared__ unsigned short Blds[64][LDA];    //  9.2 KB
    const int z  = blockIdx.z;
    const int b  = z >> 3;
    const int kc = z & 7;
    const int o0 = blockIdx.y * 128;
    const int c0 = blockIdx.x * 64;
    const int t = threadIdx.x;
    const int w = t >> 6, l = t & 63;
    const int arow = t >> 1, ahalf = t & 1;   // A staging: 2 thr/row, 32 elems each
    const int brow = t >> 2, bq = t & 3;      // B staging: 4 thr/row, 16 elems each
    const int ob = (w >> 1) * 64, cb = (w & 1) * 32;
    const int m = l & 15, kq = l >> 4;

    const unsigned short* Wp = W1b + (size_t)(o0 + arow) * K_ + kc * KCH_ + ahalf * 32;
    const unsigned short* Bp = interp_t + ((size_t)b * C2_ + (c0 + brow)) * K_ + kc * KCH_ + bq * 16;

    float4v acc[4][2] = {};

    uint4 a0 = *(const uint4*)(Wp);
    uint4 a1 = *(const uint4*)(Wp + 8);
    uint4 a2 = *(const uint4*)(Wp + 16);
    uint4 a3 = *(const uint4*)(Wp + 24);
    uint4 b0 = *(const uint4*)(Bp);
    uint4 b1 = *(const uint4*)(Bp + 8);

    for (int kk = 0; kk < KCH_; kk += 64) {
        *(uint4*)&Alds[arow][ahalf * 32]      = a0;
        *(uint4*)&Alds[arow][ahalf * 32 + 8]  = a1;
        *(uint4*)&Alds[arow][ahalf * 32 + 16] = a2;
        *(uint4*)&Alds[arow][ahalf * 32 + 24] = a3;
        *(uint4*)&Blds[brow][bq * 16]         = b0;
        *(uint4*)&Blds[brow][bq * 16 + 8]     = b1;
        __syncthreads();

        if (kk + 64 < KCH_) {
            a0 = *(const uint4*)(Wp + kk + 64);
            a1 = *(const uint4*)(Wp + kk + 72);
            a2 = *(const uint4*)(Wp + kk + 80);
            a3 = *(const uint4*)(Wp + kk + 88);
            b0 = *(const uint4*)(Bp + kk + 64);
            b1 = *(const uint4*)(Bp + kk + 72);
        }

        #pragma unroll
        for (int ks = 0; ks < 64; ks += 32) {
            short8 bf0 = *(const short8*)&Blds[cb + m][ks + kq * 8];
            short8 bf1 = *(const short8*)&Blds[cb + 16 + m][ks + kq * 8];
            #pragma unroll
            for (int mi = 0; mi < 4; ++mi) {
                short8 af = *(const short8*)&Alds[ob + mi * 16 + m][ks + kq * 8];
                acc[mi][0] = __builtin_amdgcn_mfma_f32_16x16x32_bf16(af, bf0, acc[mi][0], 0, 0, 0);
                acc[mi][1] = __builtin_amdgcn_mfma_f32_16x16x32_bf16(af, bf1, acc[mi][1], 0, 0, 0);
            }
        }
        __syncthreads();
    }

    float* Zslab = Zp + (size_t)kc * ZSLAB;
    #pragma unroll
    for (int mi = 0; mi < 4; ++mi)
    #pragma unroll
    for (int ni = 0; ni < 2; ++ni)
    #pragma unroll
    for (int r = 0; r < 4; ++r) {
        int o = o0 + ob + mi * 16 + kq * 4 + r;
        int c = c0 + cb + ni * 16 + m;
        Zslab[((size_t)b * OUT_ + o) * C2_ + c] = acc[mi][ni][r];
    }
}

// ---------------------------------------------------------------------------
// Kernel 4: reduce 8 partial slabs + bias -> final Z (slab 0), and
// accumulate BN stats (sum, sumsq per channel) via one atomic pair per block.
// ---------------------------------------------------------------------------
__global__ __launch_bounds__(256) void reduce_stats_kernel(
    float* __restrict__ Zp, const float* __restrict__ b1,
    float* __restrict__ accum)
{
    const int b  = blockIdx.x >> 4;
    const int oq = blockIdx.x & 15;
    const int c  = threadIdx.x;
    float s = 0.0f, s2 = 0.0f;
    for (int o16 = 0; o16 < 16; ++o16) {
        int o = oq * 16 + o16;
        size_t base = ((size_t)b * OUT_ + o) * C2_ + c;
        float v = b1[o];
        #pragma unroll
        for (int sl = 0; sl < SPLITK; ++sl)
            v += Zp[base + (size_t)sl * ZSLAB];
        Zp[base] = v;
        s += v; s2 += v * v;
    }
    atomicAdd(&accum[c], s);
    atomicAdd(&accum[C2_ + c], s2);
}

// ---------------------------------------------------------------------------
// Kernel 5: normalize + affine + ReLU + f32 store (reads final Z = slab 0).
// ---------------------------------------------------------------------------
__global__ __launch_bounds__(256) void bn_kernel(
    const float* __restrict__ Z, const float* __restrict__ accum,
    const float* __restrict__ gamma, const float* __restrict__ beta,
    float* __restrict__ out)
{
    const int i = (blockIdx.x * 256 + threadIdx.x) * 4;
    float4 z = *(const float4*)(Z + i);
    float vals[4] = {z.x, z.y, z.z, z.w};
    const int cb = i & 255;
    float res[4];
    #pragma unroll
    for (int j = 0; j < 4; ++j) {
        int c = cb + j;
        float mean = accum[c] * (1.0f / 4096.0f);
        float var  = accum[C2_ + c] * (1.0f / 4096.0f) - mean * mean;
        float rstd = 1.0f / sqrtf(var + 1e-5f);
        float v = gamma[c] * ((vals[j] - mean) * rstd) + beta[c];
        res[j] = fmaxf(v, 0.0f);
    }
    *(float4*)(out + i) = make_float4(res[0], res[1], res[2], res[3]);
}

// ---------------------------------------------------------------------------
extern "C" void kernel_launch(void* const* d_in, const int* in_sizes, int n_in,
                              void* d_out, int out_size, void* d_ws, size_t ws_size,
                              hipStream_t stream) {
    const float* x2    = (const float*)d_in[1];
    const float* xyz1  = (const float*)d_in[2];
    const float* xyz2  = (const float*)d_in[3];
    const float* W1    = (const float*)d_in[4];
    const float* b1    = (const float*)d_in[5];
    const float* gamma = (const float*)d_in[6];
    const float* beta  = (const float*)d_in[7];

    char* ws = (char*)d_ws;
    unsigned short* interp_t = (unsigned short*)(ws);              // 33,554,432 B
    unsigned short* W1b      = (unsigned short*)(ws + 33554432);   //  2,097,152 B
    float*          Zp       = (float*)(ws + 35651584);            // 33,554,432 B (8 slabs)
    float*          accum    = (float*)(ws + 69206016);            //      2,048 B

    knn_interp_kernel <<<2048, 256, 0, stream>>>(xyz1, xyz2, x2, interp_t,
                                                 W1, W1b, accum);
    gemm_kernel       <<<dim3(4, 2, 128), 256, 0, stream>>>(W1b, interp_t, Zp);
    reduce_stats_kernel<<<256, 256, 0, stream>>>(Zp, b1, accum);
    bn_kernel         <<<1024, 256, 0, stream>>>(Zp, accum, gamma, beta,
                                                 (float*)d_out);
}

// Round 3
// 156.836 us; speedup vs baseline: 1.0813x; 1.0813x over previous
//
#include <hip/hip_runtime.h>
#include <hip/hip_bf16.h>
#include <float.h>

#define B_    16
#define N1_   4096
#define N2_   1024
#define C2_   256
#define OUT_  256
#define K_    4096    // GEMM K == N1
#define SPLITK 8
#define KCH_  (K_ / SPLITK)     // 512
#define ZSLAB 1048576           // floats per partial slab (16*256*256)

typedef short short8 __attribute__((ext_vector_type(8)));
typedef float float4v __attribute__((ext_vector_type(4)));

static __device__ __forceinline__ unsigned short f32_to_bf16_bits(float v) {
    __hip_bfloat16 h = __float2bfloat16(v);
    return *(unsigned short*)&h;
}

static __device__ __forceinline__ void gload16(const void* g, void* l) {
    __builtin_amdgcn_global_load_lds(
        (const __attribute__((address_space(1))) unsigned int*)g,
        (__attribute__((address_space(3))) unsigned int*)l, 16, 0, 0);
}

// ---------------------------------------------------------------------------
// Fused (w1cvt + knn + interp) in ONE dispatch, block-role branch.
// R16: knn reverted verbatim to the R14 version (40.2us, 52 VGPR). R15's
// occupancy attack regressed (-37%): shfl_xor merge + two-half phase B blew
// VGPR 52->76 (waves capped at 6/SIMD, occupancy FELL) and decoalesced the
// interp_t stores to 64B/row. Keep: Q=4 queries/lane distance loop (one
// ds_read_b128 feeds 256 evals), pf[64][49] LDS merge, full 64-query
// transpose tile.
// ---------------------------------------------------------------------------
#define TPAD 65
struct KnnSh {
    float4 pts[16][65];       // per-slice padded candidates   16.64 KB
    float  pf[64][49];        // per-slice packed top-3 (q-major) 12.54 KB
};
union ShUnion {
    KnnSh a;
    unsigned short tile[C2_][TPAD];   // transpose tile  33.3 KB
};

__global__ __launch_bounds__(256) void knn_interp_kernel(
    const float* __restrict__ xyz1,
    const float* __restrict__ xyz2,
    const float* __restrict__ x2,
    unsigned short* __restrict__ interp_t,
    const float* __restrict__ W1,
    unsigned short* __restrict__ W1b,
    float* __restrict__ accum)
{
    __shared__ ShUnion sh;
    __shared__ float rw[64][3];
    __shared__ int   ri[64][3];

    const int bid = blockIdx.x;
    const int t   = threadIdx.x;

    if (bid < 1024) {   // ---- role: W1 convert (+ accum zero) ----
        if (bid == 0) {
            accum[t] = 0.0f;
            accum[256 + t] = 0.0f;
        }
        const int i = (bid * 256 + t) * 4;
        float4 v = *(const float4*)(W1 + i);
        ushort4 o;
        o.x = f32_to_bf16_bits(v.x);
        o.y = f32_to_bf16_bits(v.y);
        o.z = f32_to_bf16_bits(v.z);
        o.w = f32_to_bf16_bits(v.w);
        *(ushort4*)(W1b + i) = o;
        return;
    }

    // ---- role: knn + interp ----
    const int rem = bid - 1024;
    const int b   = rem >> 6;
    const int n0  = (rem & 63) * 64;
    const int w   = t >> 6;
    const int l   = t & 63;

    for (int r = 0; r < 4; ++r) {
        int j = r * 256 + t;
        const float* p = xyz2 + ((size_t)b * N2_ + j) * 3;
        float x = p[0], y = p[1], z = p[2];
        sh.a.pts[j >> 6][j & 63] = make_float4(x, y, z, 0.5f * ((x * x + y * y) + z * z));
    }
    __syncthreads();

    const int qg    = l & 15;           // query group: 4 queries per lane
    const int slice = (w << 2) | (l >> 4);   // 16 slices of 64 candidates
    const int jbase = slice << 6;

    // load this lane's 4 queries (12 consecutive floats, 48B aligned)
    const float* qb = xyz1 + ((size_t)b * N1_ + n0 + qg * 4) * 3;
    float4 v0 = ((const float4*)qb)[0];
    float4 v1 = ((const float4*)qb)[1];
    float4 v2 = ((const float4*)qb)[2];
    float qx[4] = {v0.x, v0.w, v1.z, v2.y};
    float qy[4] = {v0.y, v1.x, v1.w, v2.z};
    float qz[4] = {v0.z, v1.y, v2.x, v2.w};

    float ns0[4], ns1[4], ns2[4], ss[4], f[4][3];
    #pragma unroll
    for (int i = 0; i < 4; ++i) {
        ns0[i] = -qx[i]; ns1[i] = -qy[i]; ns2[i] = -qz[i];
        ss[i]  = (qx[i] * qx[i] + qy[i] * qy[i]) + qz[i] * qz[i];
        f[i][0] = FLT_MAX; f[i][1] = FLT_MAX; f[i][2] = FLT_MAX;
    }

    #pragma unroll 2
    for (int jj = 0; jj < 64; ++jj) {
        float4 pq = sh.a.pts[slice][jj];
        int j = jbase + jj;
        #pragma unroll
        for (int i = 0; i < 4; ++i) {
            float acc = fmaf(ns0[i], pq.x, pq.w);
            acc = fmaf(ns1[i], pq.y, acc);
            acc = fmaf(ns2[i], pq.z, acc);
            float dk = fmaxf(fmaf(2.0f, acc, ss[i]), 0.0f);
            float fp = __int_as_float((__float_as_int(dk) & 0xFFFFFC00) | j);
            float nf0 = fminf(fp, f[i][0]);
            float nf1 = __builtin_amdgcn_fmed3f(fp, f[i][0], f[i][1]);
            float nf2 = fminf(f[i][2], fmaxf(fp, f[i][1]));
            f[i][0] = nf0; f[i][1] = nf1; f[i][2] = nf2;
        }
    }

    #pragma unroll
    for (int i = 0; i < 4; ++i)
    #pragma unroll
    for (int r = 0; r < 3; ++r)
        sh.a.pf[qg * 4 + i][slice * 3 + r] = f[i][r];
    __syncthreads();

    if (w == 0) {
        float g0 = FLT_MAX, g1 = FLT_MAX, g2 = FLT_MAX;
        #pragma unroll 4
        for (int s = 0; s < 16; ++s)
        #pragma unroll
        for (int r = 0; r < 3; ++r) {
            float fp = sh.a.pf[l][s * 3 + r];
            float n0v = fminf(fp, g0);
            float n1v = __builtin_amdgcn_fmed3f(fp, g0, g1);
            float n2v = fminf(g2, fmaxf(fp, g1));
            g0 = n0v; g1 = n1v; g2 = n2v;
        }
        int j0 = __float_as_int(g0) & 1023;
        int j1 = __float_as_int(g1) & 1023;
        int j2 = __float_as_int(g2) & 1023;
        const float4 p0 = sh.a.pts[j0 >> 6][j0 & 63];
        const float4 p1 = sh.a.pts[j1 >> 6][j1 & 63];
        const float4 p2 = sh.a.pts[j2 >> 6][j2 & 63];
        // recompute exact distances for THIS query (lane l = local query id)
        const float* q = xyz1 + ((size_t)b * N1_ + n0 + l) * 3;
        const float s0 = q[0], s1 = q[1], s2 = q[2];
        const float ssl = (s0 * s0 + s1 * s1) + s2 * s2;
        float dd0 = ssl + 2.0f * (p0.w - ((s0 * p0.x + s1 * p0.y) + s2 * p0.z));
        float dd1 = ssl + 2.0f * (p1.w - ((s0 * p1.x + s1 * p1.y) + s2 * p1.z));
        float dd2 = ssl + 2.0f * (p2.w - ((s0 * p2.x + s1 * p2.y) + s2 * p2.z));
        float r0 = 1.0f / (dd0 + 1e-8f);
        float r1 = 1.0f / (dd1 + 1e-8f);
        float r2 = 1.0f / (dd2 + 1e-8f);
        float sden = (r0 + r1) + r2;
        rw[l][0] = r0 / sden;  rw[l][1] = r1 / sden;  rw[l][2] = r2 / sden;
        ri[l][0] = j0;         ri[l][1] = j1;         ri[l][2] = j2;
    }
    __syncthreads();   // rw/ri ready; pts/pf dead -> tile may alias

    for (int p = 0; p < 16; ++p) {
        int nl = p * 4 + w;
        float w0 = rw[nl][0], w1 = rw[nl][1], w2 = rw[nl][2];
        int i0g = ri[nl][0], i1g = ri[nl][1], i2g = ri[nl][2];
        const float4 va = ((const float4*)(x2 + ((size_t)b * N2_ + i0g) * C2_))[l];
        const float4 vb = ((const float4*)(x2 + ((size_t)b * N2_ + i1g) * C2_))[l];
        const float4 vc = ((const float4*)(x2 + ((size_t)b * N2_ + i2g) * C2_))[l];
        float fa[4] = {va.x, va.y, va.z, va.w};
        float fb[4] = {vb.x, vb.y, vb.z, vb.w};
        float fc[4] = {vc.x, vc.y, vc.z, vc.w};
        #pragma unroll
        for (int i = 0; i < 4; ++i) {
            float v = w0 * fa[i];
            v = fmaf(w1, fb[i], v);
            v = fmaf(w2, fc[i], v);
            sh.tile[l * 4 + i][nl] = f32_to_bf16_bits(v);
        }
    }
    __syncthreads();

    for (int r = 0; r < 64; ++r) {
        int c = r * 4 + w;
        interp_t[((size_t)b * C2_ + c) * K_ + n0 + l] = sh.tile[c][l];
    }
}

// ---------------------------------------------------------------------------
// Kernel 3: split-K GEMM, tile 128(o) x 64(c), BK=64 -> 8 iterations.
// R16: staging switched from reg-staged ds_write (padded LDA=72) to
// global_load_lds width-16 into LINEAR LDS (Alds[128][64], Blds[64][64],
// 24 KB) with XOR chunk-swizzle, both-sides-or-neither (rule #21):
//   write: lane (rs=l>>3, ch=l&7) of segment s stages global chunk
//          ch^rs into LDS (row=s*8+rs, chunk=ch)  [linear dest, swz source]
//   read : global (row, chunk c) lives at LDS (row, c ^ (row&7));
//          row&7 == m&7 for all fragment rows (ob/cb/mi offsets are
//          multiples of 8), so one swz value per ks step.
// Bank check: 16-lane group reads at banks 4m mod 32 -> 2-way max (free).
// m97 2-barrier structure; staging regs eliminated.
// ---------------------------------------------------------------------------
__global__ __launch_bounds__(256) void gemm_kernel(
    const unsigned short* __restrict__ W1b,
    const unsigned short* __restrict__ interp_t,
    float* __restrict__ Zp)
{
    __shared__ unsigned short Alds[128 * 64];   // 16 KB linear
    __shared__ unsigned short Blds[64 * 64];    //  8 KB linear
    const int z  = blockIdx.z;
    const int b  = z >> 3;
    const int kc = z & 7;
    const int o0 = blockIdx.y * 128;
    const int c0 = blockIdx.x * 64;
    const int t = threadIdx.x;
    const int w = t >> 6, l = t & 63;
    const int ob = (w >> 1) * 64, cb = (w & 1) * 32;
    const int m = l & 15, kq = l >> 4;

    const int rs  = l >> 3;        // row within 8-row segment
    const int ch  = l & 7;         // 16B chunk within 128B row
    const int sch = ch ^ rs;       // swizzled source chunk

    const unsigned short* Abase = W1b + (size_t)o0 * K_ + kc * KCH_ + sch * 8;
    const unsigned short* Bbase = interp_t + ((size_t)b * C2_ + c0) * K_ + kc * KCH_ + sch * 8;

    float4v acc[4][2] = {};

    for (int kk = 0; kk < KCH_; kk += 64) {
        // stage A: 16 segments of 1KB, wave w does s = w, w+4, w+8, w+12
        #pragma unroll
        for (int i = 0; i < 4; ++i) {
            int s = w + i * 4;
            gload16(Abase + (size_t)(s * 8 + rs) * K_ + kk, &Alds[s * 512 + l * 8]);
        }
        // stage B: 8 segments, wave w does s = w, w+4
        #pragma unroll
        for (int i = 0; i < 2; ++i) {
            int s = w + i * 4;
            gload16(Bbase + (size_t)(s * 8 + rs) * K_ + kk, &Blds[s * 512 + l * 8]);
        }
        __syncthreads();

        #pragma unroll
        for (int ks = 0; ks < 64; ks += 32) {
            const int swz = ((kq + (ks >> 3)) ^ (m & 7)) << 3;
            short8 bf0 = *(const short8*)&Blds[(cb + m) * 64 + swz];
            short8 bf1 = *(const short8*)&Blds[(cb + 16 + m) * 64 + swz];
            #pragma unroll
            for (int mi = 0; mi < 4; ++mi) {
                short8 af = *(const short8*)&Alds[(ob + mi * 16 + m) * 64 + swz];
                acc[mi][0] = __builtin_amdgcn_mfma_f32_16x16x32_bf16(af, bf0, acc[mi][0], 0, 0, 0);
                acc[mi][1] = __builtin_amdgcn_mfma_f32_16x16x32_bf16(af, bf1, acc[mi][1], 0, 0, 0);
            }
        }
        __syncthreads();
    }

    float* Zslab = Zp + (size_t)kc * ZSLAB;
    #pragma unroll
    for (int mi = 0; mi < 4; ++mi)
    #pragma unroll
    for (int ni = 0; ni < 2; ++ni)
    #pragma unroll
    for (int r = 0; r < 4; ++r) {
        int o = o0 + ob + mi * 16 + kq * 4 + r;
        int c = c0 + cb + ni * 16 + m;
        Zslab[((size_t)b * OUT_ + o) * C2_ + c] = acc[mi][ni][r];
    }
}

// ---------------------------------------------------------------------------
// Kernel 4: reduce 8 partial slabs + bias -> final Z (slab 0), and
// accumulate BN stats (sum, sumsq per channel) via one atomic pair per block.
// ---------------------------------------------------------------------------
__global__ __launch_bounds__(256) void reduce_stats_kernel(
    float* __restrict__ Zp, const float* __restrict__ b1,
    float* __restrict__ accum)
{
    const int b  = blockIdx.x >> 4;
    const int oq = blockIdx.x & 15;
    const int c  = threadIdx.x;
    float s = 0.0f, s2 = 0.0f;
    for (int o16 = 0; o16 < 16; ++o16) {
        int o = oq * 16 + o16;
        size_t base = ((size_t)b * OUT_ + o) * C2_ + c;
        float v = b1[o];
        #pragma unroll
        for (int sl = 0; sl < SPLITK; ++sl)
            v += Zp[base + (size_t)sl * ZSLAB];
        Zp[base] = v;
        s += v; s2 += v * v;
    }
    atomicAdd(&accum[c], s);
    atomicAdd(&accum[C2_ + c], s2);
}

// ---------------------------------------------------------------------------
// Kernel 5: normalize + affine + ReLU + f32 store (reads final Z = slab 0).
// ---------------------------------------------------------------------------
__global__ __launch_bounds__(256) void bn_kernel(
    const float* __restrict__ Z, const float* __restrict__ accum,
    const float* __restrict__ gamma, const float* __restrict__ beta,
    float* __restrict__ out)
{
    const int i = (blockIdx.x * 256 + threadIdx.x) * 4;
    float4 z = *(const float4*)(Z + i);
    float vals[4] = {z.x, z.y, z.z, z.w};
    const int cb = i & 255;
    float res[4];
    #pragma unroll
    for (int j = 0; j < 4; ++j) {
        int c = cb + j;
        float mean = accum[c] * (1.0f / 4096.0f);
        float var  = accum[C2_ + c] * (1.0f / 4096.0f) - mean * mean;
        float rstd = 1.0f / sqrtf(var + 1e-5f);
        float v = gamma[c] * ((vals[j] - mean) * rstd) + beta[c];
        res[j] = fmaxf(v, 0.0f);
    }
    *(float4*)(out + i) = make_float4(res[0], res[1], res[2], res[3]);
}

// ---------------------------------------------------------------------------
extern "C" void kernel_launch(void* const* d_in, const int* in_sizes, int n_in,
                              void* d_out, int out_size, void* d_ws, size_t ws_size,
                              hipStream_t stream) {
    const float* x2    = (const float*)d_in[1];
    const float* xyz1  = (const float*)d_in[2];
    const float* xyz2  = (const float*)d_in[3];
    const float* W1    = (const float*)d_in[4];
    const float* b1    = (const float*)d_in[5];
    const float* gamma = (const float*)d_in[6];
    const float* beta  = (const float*)d_in[7];

    char* ws = (char*)d_ws;
    unsigned short* interp_t = (unsigned short*)(ws);              // 33,554,432 B
    unsigned short* W1b      = (unsigned short*)(ws + 33554432);   //  2,097,152 B
    float*          Zp       = (float*)(ws + 35651584);            // 33,554,432 B (8 slabs)
    float*          accum    = (float*)(ws + 69206016);            //      2,048 B

    knn_interp_kernel <<<2048, 256, 0, stream>>>(xyz1, xyz2, x2, interp_t,
                                                 W1, W1b, accum);
    gemm_kernel       <<<dim3(4, 2, 128), 256, 0, stream>>>(W1b, interp_t, Zp);
    reduce_stats_kernel<<<256, 256, 0, stream>>>(Zp, b1, accum);
    bn_kernel         <<<1024, 256, 0, stream>>>(Zp, accum, gamma, beta,
                                                 (float*)d_out);
}

// Round 4
// 152.772 us; speedup vs baseline: 1.1100x; 1.0266x over previous
//
#include <hip/hip_runtime.h>
#include <hip/hip_bf16.h>
#include <float.h>

#define B_    16
#define N1_   4096
#define N2_   1024
#define C2_   256
#define OUT_  256
#define K_    4096    // GEMM K == N1
#define SPLITK 8
#define KCH_  (K_ / SPLITK)     // 512
#define ZSLAB 1048576           // floats per partial slab (16*256*256)

typedef short short8 __attribute__((ext_vector_type(8)));
typedef float float4v __attribute__((ext_vector_type(4)));

static __device__ __forceinline__ unsigned short f32_to_bf16_bits(float v) {
    __hip_bfloat16 h = __float2bfloat16(v);
    return *(unsigned short*)&h;
}

static __device__ __forceinline__ void gload16(const void* g, void* l) {
    __builtin_amdgcn_global_load_lds(
        (const __attribute__((address_space(1))) unsigned int*)g,
        (__attribute__((address_space(3))) unsigned int*)l, 16, 0, 0);
}

// ---------------------------------------------------------------------------
// Fused (w1cvt + knn + interp) in ONE dispatch, block-role branch.
// R17: XCD-locality remap (T1). FETCH_SIZE showed 50 MB over-fetch vs the
// 21 MB minimum: the 64 same-batch blocks were round-robined across all 8
// XCDs, so every XCD re-fetched x2[b] (1 MB) from HBM and phase-B gathers
// ran at L2-miss latency. New decode b = ((rem>>9)<<3)|(rem&7) pins all 64
// blocks of batch b to XCD b&7 (2 batches = 2 MB x2 resident per 4 MB L2).
// Mapping-only change: output bit-identical. knn compute unchanged from R14
// (Q=4 queries/lane distance loop, pf[64][49] merge, full transpose tile).
// ---------------------------------------------------------------------------
#define TPAD 65
struct KnnSh {
    float4 pts[16][65];       // per-slice padded candidates   16.64 KB
    float  pf[64][49];        // per-slice packed top-3 (q-major) 12.54 KB
};
union ShUnion {
    KnnSh a;
    unsigned short tile[C2_][TPAD];   // transpose tile  33.3 KB
};

__global__ __launch_bounds__(256) void knn_interp_kernel(
    const float* __restrict__ xyz1,
    const float* __restrict__ xyz2,
    const float* __restrict__ x2,
    unsigned short* __restrict__ interp_t,
    const float* __restrict__ W1,
    unsigned short* __restrict__ W1b,
    float* __restrict__ accum)
{
    __shared__ ShUnion sh;
    __shared__ float rw[64][3];
    __shared__ int   ri[64][3];

    const int bid = blockIdx.x;
    const int t   = threadIdx.x;

    if (bid < 1024) {   // ---- role: W1 convert (+ accum zero) ----
        if (bid == 0) {
            accum[t] = 0.0f;
            accum[256 + t] = 0.0f;
        }
        const int i = (bid * 256 + t) * 4;
        float4 v = *(const float4*)(W1 + i);
        ushort4 o;
        o.x = f32_to_bf16_bits(v.x);
        o.y = f32_to_bf16_bits(v.y);
        o.z = f32_to_bf16_bits(v.z);
        o.w = f32_to_bf16_bits(v.w);
        *(ushort4*)(W1b + i) = o;
        return;
    }

    // ---- role: knn + interp ----
    // XCD-pinned decode: XCD = bid%8 = rem%8 = b&7 -> same-batch blocks
    // share one XCD's L2 for the x2 gather.
    const int rem = bid - 1024;
    const int b   = ((rem >> 9) << 3) | (rem & 7);
    const int n0  = ((rem >> 3) & 63) * 64;
    const int w   = t >> 6;
    const int l   = t & 63;

    for (int r = 0; r < 4; ++r) {
        int j = r * 256 + t;
        const float* p = xyz2 + ((size_t)b * N2_ + j) * 3;
        float x = p[0], y = p[1], z = p[2];
        sh.a.pts[j >> 6][j & 63] = make_float4(x, y, z, 0.5f * ((x * x + y * y) + z * z));
    }
    __syncthreads();

    const int qg    = l & 15;           // query group: 4 queries per lane
    const int slice = (w << 2) | (l >> 4);   // 16 slices of 64 candidates
    const int jbase = slice << 6;

    // load this lane's 4 queries (12 consecutive floats, 48B aligned)
    const float* qb = xyz1 + ((size_t)b * N1_ + n0 + qg * 4) * 3;
    float4 v0 = ((const float4*)qb)[0];
    float4 v1 = ((const float4*)qb)[1];
    float4 v2 = ((const float4*)qb)[2];
    float qx[4] = {v0.x, v0.w, v1.z, v2.y};
    float qy[4] = {v0.y, v1.x, v1.w, v2.z};
    float qz[4] = {v0.z, v1.y, v2.x, v2.w};

    float ns0[4], ns1[4], ns2[4], ss[4], f[4][3];
    #pragma unroll
    for (int i = 0; i < 4; ++i) {
        ns0[i] = -qx[i]; ns1[i] = -qy[i]; ns2[i] = -qz[i];
        ss[i]  = (qx[i] * qx[i] + qy[i] * qy[i]) + qz[i] * qz[i];
        f[i][0] = FLT_MAX; f[i][1] = FLT_MAX; f[i][2] = FLT_MAX;
    }

    #pragma unroll 2
    for (int jj = 0; jj < 64; ++jj) {
        float4 pq = sh.a.pts[slice][jj];
        int j = jbase + jj;
        #pragma unroll
        for (int i = 0; i < 4; ++i) {
            float acc = fmaf(ns0[i], pq.x, pq.w);
            acc = fmaf(ns1[i], pq.y, acc);
            acc = fmaf(ns2[i], pq.z, acc);
            float dk = fmaxf(fmaf(2.0f, acc, ss[i]), 0.0f);
            float fp = __int_as_float((__float_as_int(dk) & 0xFFFFFC00) | j);
            float nf0 = fminf(fp, f[i][0]);
            float nf1 = __builtin_amdgcn_fmed3f(fp, f[i][0], f[i][1]);
            float nf2 = fminf(f[i][2], fmaxf(fp, f[i][1]));
            f[i][0] = nf0; f[i][1] = nf1; f[i][2] = nf2;
        }
    }

    #pragma unroll
    for (int i = 0; i < 4; ++i)
    #pragma unroll
    for (int r = 0; r < 3; ++r)
        sh.a.pf[qg * 4 + i][slice * 3 + r] = f[i][r];
    __syncthreads();

    if (w == 0) {
        float g0 = FLT_MAX, g1 = FLT_MAX, g2 = FLT_MAX;
        #pragma unroll 4
        for (int s = 0; s < 16; ++s)
        #pragma unroll
        for (int r = 0; r < 3; ++r) {
            float fp = sh.a.pf[l][s * 3 + r];
            float n0v = fminf(fp, g0);
            float n1v = __builtin_amdgcn_fmed3f(fp, g0, g1);
            float n2v = fminf(g2, fmaxf(fp, g1));
            g0 = n0v; g1 = n1v; g2 = n2v;
        }
        int j0 = __float_as_int(g0) & 1023;
        int j1 = __float_as_int(g1) & 1023;
        int j2 = __float_as_int(g2) & 1023;
        const float4 p0 = sh.a.pts[j0 >> 6][j0 & 63];
        const float4 p1 = sh.a.pts[j1 >> 6][j1 & 63];
        const float4 p2 = sh.a.pts[j2 >> 6][j2 & 63];
        // recompute exact distances for THIS query (lane l = local query id)
        const float* q = xyz1 + ((size_t)b * N1_ + n0 + l) * 3;
        const float s0 = q[0], s1 = q[1], s2 = q[2];
        const float ssl = (s0 * s0 + s1 * s1) + s2 * s2;
        float dd0 = ssl + 2.0f * (p0.w - ((s0 * p0.x + s1 * p0.y) + s2 * p0.z));
        float dd1 = ssl + 2.0f * (p1.w - ((s0 * p1.x + s1 * p1.y) + s2 * p1.z));
        float dd2 = ssl + 2.0f * (p2.w - ((s0 * p2.x + s1 * p2.y) + s2 * p2.z));
        float r0 = 1.0f / (dd0 + 1e-8f);
        float r1 = 1.0f / (dd1 + 1e-8f);
        float r2 = 1.0f / (dd2 + 1e-8f);
        float sden = (r0 + r1) + r2;
        rw[l][0] = r0 / sden;  rw[l][1] = r1 / sden;  rw[l][2] = r2 / sden;
        ri[l][0] = j0;         ri[l][1] = j1;         ri[l][2] = j2;
    }
    __syncthreads();   // rw/ri ready; pts/pf dead -> tile may alias

    for (int p = 0; p < 16; ++p) {
        int nl = p * 4 + w;
        float w0 = rw[nl][0], w1 = rw[nl][1], w2 = rw[nl][2];
        int i0g = ri[nl][0], i1g = ri[nl][1], i2g = ri[nl][2];
        const float4 va = ((const float4*)(x2 + ((size_t)b * N2_ + i0g) * C2_))[l];
        const float4 vb = ((const float4*)(x2 + ((size_t)b * N2_ + i1g) * C2_))[l];
        const float4 vc = ((const float4*)(x2 + ((size_t)b * N2_ + i2g) * C2_))[l];
        float fa[4] = {va.x, va.y, va.z, va.w};
        float fb[4] = {vb.x, vb.y, vb.z, vb.w};
        float fc[4] = {vc.x, vc.y, vc.z, vc.w};
        #pragma unroll
        for (int i = 0; i < 4; ++i) {
            float v = w0 * fa[i];
            v = fmaf(w1, fb[i], v);
            v = fmaf(w2, fc[i], v);
            sh.tile[l * 4 + i][nl] = f32_to_bf16_bits(v);
        }
    }
    __syncthreads();

    for (int r = 0; r < 64; ++r) {
        int c = r * 4 + w;
        interp_t[((size_t)b * C2_ + c) * K_ + n0 + l] = sh.tile[c][l];
    }
}

// ---------------------------------------------------------------------------
// Kernel 3: split-K GEMM, tile 128(o) x 64(c), BK=64 -> 8 iterations.
// global_load_lds width-16 into LINEAR LDS with XOR chunk-swizzle (R16).
// R17: grid re-dimmed (4c, 128bk, 2o) so the two o-tiles sharing the same
// interp_t B-rows have linear ids differing by 512 (== 0 mod 8) -> same
// XCD -> B fetched from HBM once (was 2x: old grid put them 4 XCDs apart).
// ---------------------------------------------------------------------------
__global__ __launch_bounds__(256) void gemm_kernel(
    const unsigned short* __restrict__ W1b,
    const unsigned short* __restrict__ interp_t,
    float* __restrict__ Zp)
{
    __shared__ unsigned short Alds[128 * 64];   // 16 KB linear
    __shared__ unsigned short Blds[64 * 64];    //  8 KB linear
    const int b  = blockIdx.y >> 3;
    const int kc = blockIdx.y & 7;
    const int o0 = blockIdx.z * 128;
    const int c0 = blockIdx.x * 64;
    const int t = threadIdx.x;
    const int w = t >> 6, l = t & 63;
    const int ob = (w >> 1) * 64, cb = (w & 1) * 32;
    const int m = l & 15, kq = l >> 4;

    const int rs  = l >> 3;        // row within 8-row segment
    const int ch  = l & 7;         // 16B chunk within 128B row
    const int sch = ch ^ rs;       // swizzled source chunk

    const unsigned short* Abase = W1b + (size_t)o0 * K_ + kc * KCH_ + sch * 8;
    const unsigned short* Bbase = interp_t + ((size_t)b * C2_ + c0) * K_ + kc * KCH_ + sch * 8;

    float4v acc[4][2] = {};

    for (int kk = 0; kk < KCH_; kk += 64) {
        // stage A: 16 segments of 1KB, wave w does s = w, w+4, w+8, w+12
        #pragma unroll
        for (int i = 0; i < 4; ++i) {
            int s = w + i * 4;
            gload16(Abase + (size_t)(s * 8 + rs) * K_ + kk, &Alds[s * 512 + l * 8]);
        }
        // stage B: 8 segments, wave w does s = w, w+4
        #pragma unroll
        for (int i = 0; i < 2; ++i) {
            int s = w + i * 4;
            gload16(Bbase + (size_t)(s * 8 + rs) * K_ + kk, &Blds[s * 512 + l * 8]);
        }
        __syncthreads();

        #pragma unroll
        for (int ks = 0; ks < 64; ks += 32) {
            const int swz = ((kq + (ks >> 3)) ^ (m & 7)) << 3;
            short8 bf0 = *(const short8*)&Blds[(cb + m) * 64 + swz];
            short8 bf1 = *(const short8*)&Blds[(cb + 16 + m) * 64 + swz];
            #pragma unroll
            for (int mi = 0; mi < 4; ++mi) {
                short8 af = *(const short8*)&Alds[(ob + mi * 16 + m) * 64 + swz];
                acc[mi][0] = __builtin_amdgcn_mfma_f32_16x16x32_bf16(af, bf0, acc[mi][0], 0, 0, 0);
                acc[mi][1] = __builtin_amdgcn_mfma_f32_16x16x32_bf16(af, bf1, acc[mi][1], 0, 0, 0);
            }
        }
        __syncthreads();
    }

    float* Zslab = Zp + (size_t)kc * ZSLAB;
    #pragma unroll
    for (int mi = 0; mi < 4; ++mi)
    #pragma unroll
    for (int ni = 0; ni < 2; ++ni)
    #pragma unroll
    for (int r = 0; r < 4; ++r) {
        int o = o0 + ob + mi * 16 + kq * 4 + r;
        int c = c0 + cb + ni * 16 + m;
        Zslab[((size_t)b * OUT_ + o) * C2_ + c] = acc[mi][ni][r];
    }
}

// ---------------------------------------------------------------------------
// Kernel 4: reduce 8 partial slabs + bias -> final Z (slab 0), and
// accumulate BN stats (sum, sumsq per channel) via one atomic pair per block.
// ---------------------------------------------------------------------------
__global__ __launch_bounds__(256) void reduce_stats_kernel(
    float* __restrict__ Zp, const float* __restrict__ b1,
    float* __restrict__ accum)
{
    const int b  = blockIdx.x >> 4;
    const int oq = blockIdx.x & 15;
    const int c  = threadIdx.x;
    float s = 0.0f, s2 = 0.0f;
    for (int o16 = 0; o16 < 16; ++o16) {
        int o = oq * 16 + o16;
        size_t base = ((size_t)b * OUT_ + o) * C2_ + c;
        float v = b1[o];
        #pragma unroll
        for (int sl = 0; sl < SPLITK; ++sl)
            v += Zp[base + (size_t)sl * ZSLAB];
        Zp[base] = v;
        s += v; s2 += v * v;
    }
    atomicAdd(&accum[c], s);
    atomicAdd(&accum[C2_ + c], s2);
}

// ---------------------------------------------------------------------------
// Kernel 5: normalize + affine + ReLU + f32 store (reads final Z = slab 0).
// ---------------------------------------------------------------------------
__global__ __launch_bounds__(256) void bn_kernel(
    const float* __restrict__ Z, const float* __restrict__ accum,
    const float* __restrict__ gamma, const float* __restrict__ beta,
    float* __restrict__ out)
{
    const int i = (blockIdx.x * 256 + threadIdx.x) * 4;
    float4 z = *(const float4*)(Z + i);
    float vals[4] = {z.x, z.y, z.z, z.w};
    const int cb = i & 255;
    float res[4];
    #pragma unroll
    for (int j = 0; j < 4; ++j) {
        int c = cb + j;
        float mean = accum[c] * (1.0f / 4096.0f);
        float var  = accum[C2_ + c] * (1.0f / 4096.0f) - mean * mean;
        float rstd = 1.0f / sqrtf(var + 1e-5f);
        float v = gamma[c] * ((vals[j] - mean) * rstd) + beta[c];
        res[j] = fmaxf(v, 0.0f);
    }
    *(float4*)(out + i) = make_float4(res[0], res[1], res[2], res[3]);
}

// ---------------------------------------------------------------------------
extern "C" void kernel_launch(void* const* d_in, const int* in_sizes, int n_in,
                              void* d_out, int out_size, void* d_ws, size_t ws_size,
                              hipStream_t stream) {
    const float* x2    = (const float*)d_in[1];
    const float* xyz1  = (const float*)d_in[2];
    const float* xyz2  = (const float*)d_in[3];
    const float* W1    = (const float*)d_in[4];
    const float* b1    = (const float*)d_in[5];
    const float* gamma = (const float*)d_in[6];
    const float* beta  = (const float*)d_in[7];

    char* ws = (char*)d_ws;
    unsigned short* interp_t = (unsigned short*)(ws);              // 33,554,432 B
    unsigned short* W1b      = (unsigned short*)(ws + 33554432);   //  2,097,152 B
    float*          Zp       = (float*)(ws + 35651584);            // 33,554,432 B (8 slabs)
    float*          accum    = (float*)(ws + 69206016);            //      2,048 B

    knn_interp_kernel <<<2048, 256, 0, stream>>>(xyz1, xyz2, x2, interp_t,
                                                 W1, W1b, accum);
    gemm_kernel       <<<dim3(4, 128, 2), 256, 0, stream>>>(W1b, interp_t, Zp);
    reduce_stats_kernel<<<256, 256, 0, stream>>>(Zp, b1, accum);
    bn_kernel         <<<1024, 256, 0, stream>>>(Zp, accum, gamma, beta,
                                                 (float*)d_out);
}